// Round 2
// baseline (393.142 us; speedup 1.0000x reference)
//
#include <hip/hip_runtime.h>
#include <hip/hip_bf16.h>

#define N 8192
#define F_IN 256
#define F_HID 64
#define F_LAT 32

// ---------------- CSR construction ----------------

__global__ void k_count(const int* __restrict__ ei, int* __restrict__ deg, int Ecnt) {
    int e = blockIdx.x * 256 + threadIdx.x;
    if (e < Ecnt) {
        int d = ei[Ecnt + e];  // dst
        atomicAdd(&deg[d], 1);
    }
}

// single block, 1024 threads: exclusive scan of deg -> off, and dinv = rsqrt(deg+1)
__global__ __launch_bounds__(1024) void k_scan(const int* __restrict__ deg,
                                               int* __restrict__ off,
                                               float* __restrict__ dinv) {
    __shared__ int sm[1024];
    __shared__ int carry;
    int tid = threadIdx.x;
    if (tid == 0) carry = 0;
    __syncthreads();
    for (int base = 0; base < N; base += 1024) {
        int v = deg[base + tid];
        dinv[base + tid] = rsqrtf((float)v + 1.0f);  // +1 self loop
        sm[tid] = v;
        __syncthreads();
        for (int s = 1; s < 1024; s <<= 1) {
            int t = (tid >= s) ? sm[tid - s] : 0;
            __syncthreads();
            sm[tid] += t;
            __syncthreads();
        }
        off[base + tid] = carry + sm[tid] - v;  // exclusive
        __syncthreads();
        if (tid == 1023) carry += sm[1023];
        __syncthreads();
    }
    if (tid == 0) off[N] = carry;
}

__global__ void k_fill(const int* __restrict__ ei, const int* __restrict__ off,
                       int* __restrict__ cursor, int* __restrict__ csr, int Ecnt) {
    int e = blockIdx.x * 256 + threadIdx.x;
    if (e < Ecnt) {
        int s = ei[e];
        int d = ei[Ecnt + e];
        int pos = off[d] + atomicAdd(&cursor[d], 1);
        csr[pos] = s;
    }
}

// ---------------- GEMM 1: ts = (x @ W1) * dinv[row]  [N,64] ----------------
// grid N/16 = 512 blocks, 256 threads. 16 rows/block, each thread 4 rows x 1 col.
__global__ __launch_bounds__(256) void k_gemm1(const float* __restrict__ x,
                                               const float* __restrict__ W1,
                                               const float* __restrict__ dinv,
                                               float* __restrict__ ts) {
    __shared__ float xs[16 * 256];
    int tid = threadIdx.x;
    int r0 = blockIdx.x * 16;
    for (int i = tid; i < 1024; i += 256)
        ((float4*)xs)[i] = ((const float4*)(x + (size_t)r0 * 256))[i];
    __syncthreads();
    int c = tid & 63;
    int rb = tid >> 6;  // 0..3 -> rows rb, rb+4, rb+8, rb+12
    float a0 = 0.f, a1 = 0.f, a2 = 0.f, a3 = 0.f;
    for (int k = 0; k < 256; k += 4) {
        float4 x0 = *(const float4*)(&xs[(rb + 0) * 256 + k]);
        float4 x1 = *(const float4*)(&xs[(rb + 4) * 256 + k]);
        float4 x2 = *(const float4*)(&xs[(rb + 8) * 256 + k]);
        float4 x3 = *(const float4*)(&xs[(rb + 12) * 256 + k]);
        float w0 = W1[(k + 0) * 64 + c];
        float w1 = W1[(k + 1) * 64 + c];
        float w2 = W1[(k + 2) * 64 + c];
        float w3 = W1[(k + 3) * 64 + c];
        a0 = fmaf(x0.x, w0, fmaf(x0.y, w1, fmaf(x0.z, w2, fmaf(x0.w, w3, a0))));
        a1 = fmaf(x1.x, w0, fmaf(x1.y, w1, fmaf(x1.z, w2, fmaf(x1.w, w3, a1))));
        a2 = fmaf(x2.x, w0, fmaf(x2.y, w1, fmaf(x2.z, w2, fmaf(x2.w, w3, a2))));
        a3 = fmaf(x3.x, w0, fmaf(x3.y, w1, fmaf(x3.z, w2, fmaf(x3.w, w3, a3))));
    }
    ts[(r0 + rb + 0)  * 64 + c] = a0 * dinv[r0 + rb + 0];
    ts[(r0 + rb + 4)  * 64 + c] = a1 * dinv[r0 + rb + 4];
    ts[(r0 + rb + 8)  * 64 + c] = a2 * dinv[r0 + rb + 8];
    ts[(r0 + rb + 12) * 64 + c] = a3 * dinv[r0 + rb + 12];
}

// ---------------- Aggregation 1: h = relu(dinv[i]*(ts[i] + sum ts[src]) + b1) ----------------
// grid N/4 = 2048 blocks, 256 threads (1 node per wave; lane = feature).
__global__ __launch_bounds__(256) void k_agg1(const float* __restrict__ ts,
                                              const int* __restrict__ off,
                                              const int* __restrict__ csr,
                                              const float* __restrict__ dinv,
                                              const float* __restrict__ b1,
                                              float* __restrict__ h) {
    int i = blockIdx.x * 4 + (threadIdx.x >> 6);
    int c = threadIdx.x & 63;
    float acc = ts[i * 64 + c];  // self-loop term (pre-scaled by dinv[i])
    int e0 = off[i], e1 = off[i + 1];
    int e = e0;
    for (; e + 4 <= e1; e += 4) {
        int s0 = csr[e], s1 = csr[e + 1], s2 = csr[e + 2], s3 = csr[e + 3];
        float v0 = ts[s0 * 64 + c];
        float v1 = ts[s1 * 64 + c];
        float v2 = ts[s2 * 64 + c];
        float v3 = ts[s3 * 64 + c];
        acc += v0 + v1 + v2 + v3;
    }
    for (; e < e1; ++e) acc += ts[csr[e] * 64 + c];
    h[i * 64 + c] = fmaxf(acc * dinv[i] + b1[c], 0.f);
}

// ---------------- GEMM 2: ps = (h @ [Wmu|Wls]) * dinv[row]  [N,64] ----------------
__global__ __launch_bounds__(256) void k_gemm2(const float* __restrict__ h,
                                               const float* __restrict__ Wmu,
                                               const float* __restrict__ Wls,
                                               const float* __restrict__ dinv,
                                               float* __restrict__ ps) {
    __shared__ float hs[16 * 64];
    int tid = threadIdx.x;
    int r0 = blockIdx.x * 16;
    for (int i = tid; i < 256; i += 256)
        ((float4*)hs)[i] = ((const float4*)(h + (size_t)r0 * 64))[i];
    __syncthreads();
    int c = tid & 63;
    int rb = tid >> 6;
    const float* W = (c < 32) ? Wmu : Wls;
    int cc = c & 31;
    float a0 = 0.f, a1 = 0.f, a2 = 0.f, a3 = 0.f;
    for (int k = 0; k < 64; k += 4) {
        float4 x0 = *(const float4*)(&hs[(rb + 0) * 64 + k]);
        float4 x1 = *(const float4*)(&hs[(rb + 4) * 64 + k]);
        float4 x2 = *(const float4*)(&hs[(rb + 8) * 64 + k]);
        float4 x3 = *(const float4*)(&hs[(rb + 12) * 64 + k]);
        float w0 = W[(k + 0) * 32 + cc];
        float w1 = W[(k + 1) * 32 + cc];
        float w2 = W[(k + 2) * 32 + cc];
        float w3 = W[(k + 3) * 32 + cc];
        a0 = fmaf(x0.x, w0, fmaf(x0.y, w1, fmaf(x0.z, w2, fmaf(x0.w, w3, a0))));
        a1 = fmaf(x1.x, w0, fmaf(x1.y, w1, fmaf(x1.z, w2, fmaf(x1.w, w3, a1))));
        a2 = fmaf(x2.x, w0, fmaf(x2.y, w1, fmaf(x2.z, w2, fmaf(x2.w, w3, a2))));
        a3 = fmaf(x3.x, w0, fmaf(x3.y, w1, fmaf(x3.z, w2, fmaf(x3.w, w3, a3))));
    }
    ps[(r0 + rb + 0)  * 64 + c] = a0 * dinv[r0 + rb + 0];
    ps[(r0 + rb + 4)  * 64 + c] = a1 * dinv[r0 + rb + 4];
    ps[(r0 + rb + 8)  * 64 + c] = a2 * dinv[r0 + rb + 8];
    ps[(r0 + rb + 12) * 64 + c] = a3 * dinv[r0 + rb + 12];
}

// ---------------- Aggregation 2 + reparameterize: z = mu + eps*exp(logstd) ----------------
__global__ __launch_bounds__(256) void k_agg2(const float* __restrict__ ps,
                                              const int* __restrict__ off,
                                              const int* __restrict__ csr,
                                              const float* __restrict__ dinv,
                                              const float* __restrict__ bmu,
                                              const float* __restrict__ bls,
                                              const float* __restrict__ eps,
                                              float* __restrict__ z) {
    int i = blockIdx.x * 4 + (threadIdx.x >> 6);
    int c = threadIdx.x & 63;
    float acc = ps[i * 64 + c];
    int e0 = off[i], e1 = off[i + 1];
    int e = e0;
    for (; e + 4 <= e1; e += 4) {
        int s0 = csr[e], s1 = csr[e + 1], s2 = csr[e + 2], s3 = csr[e + 3];
        float v0 = ps[s0 * 64 + c];
        float v1 = ps[s1 * 64 + c];
        float v2 = ps[s2 * 64 + c];
        float v3 = ps[s3 * 64 + c];
        acc += v0 + v1 + v2 + v3;
    }
    for (; e < e1; ++e) acc += ps[csr[e] * 64 + c];
    float bias = (c < 32) ? bmu[c] : bls[c - 32];
    acc = acc * dinv[i] + bias;            // lanes 0..31: mu, 32..63: logstd
    float ls = __shfl(acc, c | 32, 64);    // each low lane pulls its logstd
    if (c < 32) {
        z[i * 32 + c] = acc + eps[i * 32 + c] * __expf(ls);
    }
}

// ---------------- Decode: adj = sigmoid(z @ z^T)  [N,N] ----------------
// 128x128 tile per block of 256 threads; 8x8 register blocking; K=32.
__global__ __launch_bounds__(256) void k_decode(const float* __restrict__ z,
                                                float* __restrict__ adj) {
    __shared__ float zr[128 * 36];
    __shared__ float zc[128 * 36];
    int tid = threadIdx.x;
    int tR = blockIdx.y * 128;
    int tC = blockIdx.x * 128;
    for (int idx = tid; idx < 1024; idx += 256) {
        int row = idx >> 3, k4 = idx & 7;
        float4 a = *(const float4*)(z + (size_t)(tR + row) * 32 + k4 * 4);
        float4 b = *(const float4*)(z + (size_t)(tC + row) * 32 + k4 * 4);
        *(float4*)(&zr[row * 36 + k4 * 4]) = a;
        *(float4*)(&zc[row * 36 + k4 * 4]) = b;
    }
    __syncthreads();
    int tc = tid & 15;   // col group: cols tc + 16*j
    int tr = tid >> 4;   // row group: rows tr + 16*i
    float acc[8][8];
#pragma unroll
    for (int i = 0; i < 8; ++i)
#pragma unroll
        for (int j = 0; j < 8; ++j) acc[i][j] = 0.f;

    for (int kk = 0; kk < 8; ++kk) {
        float4 ar[8], bc[8];
#pragma unroll
        for (int i = 0; i < 8; ++i)
            ar[i] = *(const float4*)(&zr[(tr + i * 16) * 36 + kk * 4]);
#pragma unroll
        for (int j = 0; j < 8; ++j)
            bc[j] = *(const float4*)(&zc[(tc + j * 16) * 36 + kk * 4]);
#pragma unroll
        for (int i = 0; i < 8; ++i)
#pragma unroll
            for (int j = 0; j < 8; ++j) {
                acc[i][j] = fmaf(ar[i].x, bc[j].x, acc[i][j]);
                acc[i][j] = fmaf(ar[i].y, bc[j].y, acc[i][j]);
                acc[i][j] = fmaf(ar[i].z, bc[j].z, acc[i][j]);
                acc[i][j] = fmaf(ar[i].w, bc[j].w, acc[i][j]);
            }
    }
#pragma unroll
    for (int i = 0; i < 8; ++i) {
        int row = tR + tr + i * 16;
        float* outrow = adj + (size_t)row * N + tC;
#pragma unroll
        for (int j = 0; j < 8; ++j) {
            float t = __expf(-acc[i][j]);
            outrow[tc + j * 16] = 1.0f / (1.0f + t);
        }
    }
}

extern "C" void kernel_launch(void* const* d_in, const int* in_sizes, int n_in,
                              void* d_out, int out_size, void* d_ws, size_t ws_size,
                              hipStream_t stream) {
    const float* x   = (const float*)d_in[0];
    const int*   ei  = (const int*)d_in[1];
    const float* W1  = (const float*)d_in[2];
    const float* b1  = (const float*)d_in[3];
    const float* Wmu = (const float*)d_in[4];
    const float* bmu = (const float*)d_in[5];
    const float* Wls = (const float*)d_in[6];
    const float* bls = (const float*)d_in[7];
    const float* eps = (const float*)d_in[8];
    float* adj = (float*)d_out;
    const int Ecnt = in_sizes[1] >> 1;

    char* ws = (char*)d_ws;
    int*   deg    = (int*)(ws);                       // 32 KB
    int*   cursor = (int*)(ws + (32 << 10));          // 32 KB
    int*   off    = (int*)(ws + (64 << 10));          // 32 KB+4 (reserve 64 KB)
    int*   csr    = (int*)(ws + (128 << 10));         // E*4 = 1 MB
    float* dinv   = (float*)(ws + (128 << 10) + (1 << 20));           // 32 KB
    float* ts     = (float*)(ws + (160 << 10) + (1 << 20));           // 2 MB
    float* h      = ts + (size_t)N * 64;                              // 2 MB
    float* ps     = h + (size_t)N * 64;                               // 2 MB
    float* zbuf   = ps + (size_t)N * 64;                              // 1 MB

    hipMemsetAsync(deg, 0, 64 << 10, stream);  // deg + cursor

    k_count<<<dim3((Ecnt + 255) / 256), dim3(256), 0, stream>>>(ei, deg, Ecnt);
    k_scan<<<dim3(1), dim3(1024), 0, stream>>>(deg, off, dinv);
    k_fill<<<dim3((Ecnt + 255) / 256), dim3(256), 0, stream>>>(ei, off, cursor, csr, Ecnt);

    k_gemm1<<<dim3(N / 16), dim3(256), 0, stream>>>(x, W1, dinv, ts);
    k_agg1 <<<dim3(N / 4),  dim3(256), 0, stream>>>(ts, off, csr, dinv, b1, h);
    k_gemm2<<<dim3(N / 16), dim3(256), 0, stream>>>(h, Wmu, Wls, dinv, ps);
    k_agg2 <<<dim3(N / 4),  dim3(256), 0, stream>>>(ps, off, csr, dinv, bmu, bls, eps, zbuf);

    k_decode<<<dim3(N / 128, N / 128), dim3(256), 0, stream>>>(zbuf, adj);
}